// Round 1
// baseline (1304.379 us; speedup 1.0000x reference)
//
#include <hip/hip_runtime.h>
#include <stdint.h>

typedef float f32x4 __attribute__((ext_vector_type(4)));
typedef short short8 __attribute__((ext_vector_type(8)));

__device__ __forceinline__ unsigned short f2bf(float f){
  union { float f; unsigned int u; } v; v.f = f;
  unsigned int r = v.u + 0x7fffu + ((v.u >> 16) & 1u);
  return (unsigned short)(r >> 16);
}

__device__ __forceinline__ void async16(void* lds, const void* g){
  __builtin_amdgcn_global_load_lds(
      (const __attribute__((address_space(1))) void*)g,
      (__attribute__((address_space(3))) void*)lds, 16, 0, 0);
}

// ---------------- f32 -> bf16 conversion ----------------
__global__ void cvt_f32_bf16(const float* __restrict__ in, unsigned short* __restrict__ out, int n4){
  int i = blockIdx.x * 256 + threadIdx.x;
  const int stride = gridDim.x * 256;
  for (; i < n4; i += stride){
    const float4 v = ((const float4*)in)[i];
    ushort4 o;
    o.x = f2bf(v.x); o.y = f2bf(v.y); o.z = f2bf(v.z); o.w = f2bf(v.w);
    ((ushort4*)out)[i] = o;
  }
}

// ---------------- mask dtype detector ----------------
// mode 0: int32 0/1.  mode 1: bytes 0/1.  mode 2: f32 0.0/1.0
__global__ void detect_mask(const unsigned int* __restrict__ mask, int* __restrict__ flag){
  __shared__ int fbyte, ff32;
  const int tid = threadIdx.x;
  if (tid == 0){ fbyte = 0; ff32 = 0; }
  __syncthreads();
  int lb = 0, lf = 0;
  for (int i = tid; i < 65536; i += 256){
    unsigned int w = mask[i];
    if (w == 0x3f800000u) lf = 1;
    else if (w > 1u) lb = 1;
  }
  if (lf) atomicOr(&ff32, 1);
  if (lb) atomicOr(&fbyte, 1);
  __syncthreads();
  if (tid == 0) *flag = ff32 ? 2 : (fbyte ? 1 : 0);
}

// ---------------- batched GEMM  C = A * B^T  (A:[M,K] rm, B:[N,K] rm) ----------------
// EPI 0: f32 store   1: (acc+bias[col])*scale[col] -> bf16   2: acc+bias[col] -> bf16   3: bf16
#define BM 128
#define BN 128
#define BK 32

template<int EPI>
__global__ __launch_bounds__(256) void gemm_bt(
    const unsigned short* __restrict__ A,
    const unsigned short* __restrict__ B,
    void* __restrict__ C,
    int K, int lda, int ldb, int ldc,
    long sA, long sB, long sC,
    const float* __restrict__ bias,
    const float* __restrict__ scale)
{
  __shared__ unsigned short As[BM*BK];
  __shared__ unsigned short Bs[BN*BK];
  const int bz = blockIdx.z;
  A += (long)bz * sA;
  B += (long)bz * sB;
  const int bm = blockIdx.y, bn = blockIdx.x;
  const int tid = threadIdx.x;
  const int lane = tid & 63, wave = tid >> 6;
  const int wr = wave >> 1, wc = wave & 1;

  const unsigned short* Ag = A + ((long)(bm*BM + (tid>>2)))*lda + (tid&3)*8;
  const unsigned short* Bg = B + ((long)(bn*BN + (tid>>2)))*ldb + (tid&3)*8;
  unsigned short* Asl = &As[(tid>>2)*BK + (tid&3)*8];
  unsigned short* Bsl = &Bs[(tid>>2)*BK + (tid&3)*8];
  const long a64 = 64l * lda, b64 = 64l * ldb;

  f32x4 acc[4][4];
  #pragma unroll
  for (int i=0;i<4;i++)
    #pragma unroll
    for (int j=0;j<4;j++)
      acc[i][j] = {0.f,0.f,0.f,0.f};

  for (int k0 = 0; k0 < K; k0 += BK){
    __syncthreads();
    async16(Asl,          Ag + k0);
    async16(Asl + 64*BK,  Ag + a64 + k0);
    async16(Bsl,          Bg + k0);
    async16(Bsl + 64*BK,  Bg + b64 + k0);
    asm volatile("s_waitcnt vmcnt(0)" ::: "memory");
    __syncthreads();

    const int fr = lane & 15, fk = (lane >> 4) * 8;
    short8 af[4], bf[4];
    #pragma unroll
    for (int i=0;i<4;i++)
      af[i] = *(const short8*)&As[(wr*64 + i*16 + fr)*BK + fk];
    #pragma unroll
    for (int i=0;i<4;i++)
      bf[i] = *(const short8*)&Bs[(wc*64 + i*16 + fr)*BK + fk];
    #pragma unroll
    for (int i=0;i<4;i++)
      #pragma unroll
      for (int j=0;j<4;j++)
        acc[i][j] = __builtin_amdgcn_mfma_f32_16x16x32_bf16(af[i], bf[j], acc[i][j], 0, 0, 0);
  }

  const int cr0 = (lane >> 4) * 4, cc0 = lane & 15;
  const long rowb = bm*BM + wr*64;
  const long colb = bn*BN + wc*64;
  #pragma unroll
  for (int i=0;i<4;i++){
    #pragma unroll
    for (int j=0;j<4;j++){
      #pragma unroll
      for (int r=0;r<4;r++){
        const long row = rowb + i*16 + cr0 + r;
        const long col = colb + j*16 + cc0;
        const float v = acc[i][j][r];
        if (EPI == 0){
          ((float*)C)[(long)bz*sC + row*ldc + col] = v;
        } else if (EPI == 1){
          ((unsigned short*)C)[(long)bz*sC + row*ldc + col] = f2bf((v + bias[col]) * scale[col]);
        } else if (EPI == 2){
          ((unsigned short*)C)[(long)bz*sC + row*ldc + col] = f2bf(v + bias[col]);
        } else {
          ((unsigned short*)C)[(long)bz*sC + row*ldc + col] = f2bf(v);
        }
      }
    }
  }
}

// ---------------- fused mask + row softmax (in-place, writes bf16 E) ----------------
__global__ __launch_bounds__(256) void mask_softmax(
    float* __restrict__ UV, const void* __restrict__ mask, const int* __restrict__ flag)
{
  const long row = blockIdx.x;                 // b*3072 + i
  float* r = UV + row * 3072l;
  const long moff = row * 3072l;
  const int mode = *flag;
  const int tid = threadIdx.x;

  float x[12]; bool msk[12];
  #pragma unroll
  for (int i=0;i<12;i++) x[i] = r[tid + i*256];

  if (mode == 0){
    const int* mp = (const int*)mask + moff;
    #pragma unroll
    for (int i=0;i<12;i++) msk[i] = mp[tid + i*256] != 0;
  } else if (mode == 1){
    const unsigned char* mp = (const unsigned char*)mask + moff;
    #pragma unroll
    for (int i=0;i<12;i++) msk[i] = mp[tid + i*256] != 0;
  } else {
    const float* mp = (const float*)mask + moff;
    #pragma unroll
    for (int i=0;i<12;i++) msk[i] = mp[tid + i*256] != 0.f;
  }

  float mx = -3.0e38f;
  #pragma unroll
  for (int i=0;i<12;i++) if (!msk[i]) mx = fmaxf(mx, x[i]);
  #pragma unroll
  for (int o=1;o<64;o<<=1) mx = fmaxf(mx, __shfl_xor(mx, o, 64));
  __shared__ float sm[4];
  __shared__ float ss[4];
  if ((tid & 63) == 0) sm[tid >> 6] = mx;
  __syncthreads();
  mx = fmaxf(fmaxf(sm[0], sm[1]), fmaxf(sm[2], sm[3]));

  float e[12]; float s = 0.f;
  #pragma unroll
  for (int i=0;i<12;i++){ e[i] = msk[i] ? 0.f : __expf(x[i] - mx); s += e[i]; }
  #pragma unroll
  for (int o=1;o<64;o<<=1) s += __shfl_xor(s, o, 64);
  if ((tid & 63) == 0) ss[tid >> 6] = s;
  __syncthreads();
  s = ss[0] + ss[1] + ss[2] + ss[3];
  const float inv = 1.f / s;

  unsigned short* o = (unsigned short*)r;      // in-place: bf16 row at lda=6144
  #pragma unroll
  for (int i=0;i<12;i++) o[tid + i*256] = f2bf(e[i] * inv);
}

// ---------------- LayerNorm(M=512) + ReLU -> bf16 ----------------
__global__ __launch_bounds__(256) void ln_relu(
    const float* __restrict__ fe, unsigned short* __restrict__ out,
    const float* __restrict__ g, const float* __restrict__ b)
{
  const long row = blockIdx.x;
  const float* r = fe + row * 512l;
  const int tid = threadIdx.x;
  const float x0 = r[tid], x1 = r[tid + 256];
  float s = x0 + x1;
  float s2 = x0*x0 + x1*x1;
  #pragma unroll
  for (int o=1;o<64;o<<=1){ s += __shfl_xor(s, o, 64); s2 += __shfl_xor(s2, o, 64); }
  __shared__ float sa[4], sb[4];
  if ((tid & 63) == 0){ sa[tid>>6] = s; sb[tid>>6] = s2; }
  __syncthreads();
  s  = sa[0] + sa[1] + sa[2] + sa[3];
  s2 = sb[0] + sb[1] + sb[2] + sb[3];
  const float mean = s * (1.f/512.f);
  const float var  = s2 * (1.f/512.f) - mean*mean;
  const float rstd = rsqrtf(var + 1e-5f);
  const float y0 = (x0 - mean) * rstd * g[tid]       + b[tid];
  const float y1 = (x1 - mean) * rstd * g[tid + 256] + b[tid + 256];
  out[row*512 + tid]       = f2bf(fmaxf(y0, 0.f));
  out[row*512 + tid + 256] = f2bf(fmaxf(y1, 0.f));
}

// ---------------- host launcher ----------------
extern "C" void kernel_launch(void* const* d_in, const int* in_sizes, int n_in,
                              void* d_out, int out_size, void* d_ws, size_t ws_size,
                              hipStream_t stream)
{
  const float* feature = (const float*)d_in[0];
  const void*  mask    = d_in[1];
  const float* U_w  = (const float*)d_in[2];
  const float* U_b  = (const float*)d_in[3];
  const float* V_w  = (const float*)d_in[4];
  const float* V_b  = (const float*)d_in[5];
  const float* w_a  = (const float*)d_in[6];
  const float* W_e2 = (const float*)d_in[7];
  const float* W_e1 = (const float*)d_in[8];
  const float* ln_g = (const float*)d_in[9];
  const float* ln_b = (const float*)d_in[10];

  // B=8, TN=3072, D=1024, M=512
  char* w = (char*)d_ws;
  int*            flag = (int*)w;                                   // 256 B
  unsigned short* fbf  = (unsigned short*)(w + 256);                // 8*3072*1024 bf16
  unsigned short* Uwb  = fbf  + 25165824;                           // 1024*1024
  unsigned short* Vwb  = Uwb  + 1048576;
  unsigned short* We2b = Vwb  + 1048576;                            // 512*1024
  unsigned short* We1b = We2b + 524288;                             // 1024*512
  unsigned short* fUb  = We1b + 524288;                             // 8*3072*1024
  unsigned short* fVb  = fUb  + 25165824;
  float*          UV   = (float*)(fVb + 25165824);                  // 8*3072*3072 f32
  unsigned short* fWT  = (unsigned short*)(UV + 75497472);          // 8*512*3072
  float*          fe   = (float*)fUb;                               // alias (fU dead after UV)
  unsigned short* fact = fVb;                                       // alias (fV dead after UV)

  cvt_f32_bf16<<<2048, 256, 0, stream>>>(feature, fbf, 25165824/4);
  cvt_f32_bf16<<<512,  256, 0, stream>>>(U_w,  Uwb,  1048576/4);
  cvt_f32_bf16<<<512,  256, 0, stream>>>(V_w,  Vwb,  1048576/4);
  cvt_f32_bf16<<<256,  256, 0, stream>>>(W_e2, We2b, 524288/4);
  cvt_f32_bf16<<<256,  256, 0, stream>>>(W_e1, We1b, 524288/4);
  detect_mask<<<1, 256, 0, stream>>>((const unsigned int*)mask, flag);

  // fU = (f @ U_w^T + U_b) * w_a      [3072,1024] bf16 per batch
  gemm_bt<1><<<dim3(8,24,8), 256, 0, stream>>>(fbf, Uwb, fUb,
      1024, 1024, 1024, 1024, 3072l*1024, 0, 3072l*1024, U_b, w_a);
  // fV = f @ V_w^T + V_b
  gemm_bt<2><<<dim3(8,24,8), 256, 0, stream>>>(fbf, Vwb, fVb,
      1024, 1024, 1024, 1024, 3072l*1024, 0, 3072l*1024, V_b, nullptr);
  // UV = fU @ fV^T   [3072,3072] f32 per batch
  gemm_bt<0><<<dim3(24,24,8), 256, 0, stream>>>(fUb, fVb, UV,
      1024, 1024, 1024, 3072, 3072l*1024, 3072l*1024, 3072l*3072, nullptr, nullptr);
  // E = softmax(mask ? -inf : UV)  -> bf16 in-place (row stride 6144 ushorts)
  mask_softmax<<<24576, 256, 0, stream>>>(UV, mask, flag);
  // fWT = W_e2 @ f^T   [512,3072] bf16 per batch
  gemm_bt<3><<<dim3(24,4,8), 256, 0, stream>>>(We2b, fbf, fWT,
      1024, 1024, 1024, 3072, 0, 3072l*1024, 512l*3072, nullptr, nullptr);
  // fe = E @ fWT^T   [3072,512] f32 per batch
  gemm_bt<0><<<dim3(4,24,8), 256, 0, stream>>>((const unsigned short*)UV, fWT, fe,
      3072, 6144, 3072, 512, 3072l*6144, 512l*3072, 3072l*512, nullptr, nullptr);
  // LN + ReLU -> bf16
  ln_relu<<<24576, 256, 0, stream>>>(fe, fact, ln_g, ln_b);
  // out = fe_act @ W_e1^T   [3072,1024] f32
  gemm_bt<0><<<dim3(8,24,8), 256, 0, stream>>>(fact, We1b, (float*)d_out,
      512, 512, 512, 1024, 3072l*512, 0, 3072l*1024, nullptr, nullptr);
}

// Round 2
// 1212.106 us; speedup vs baseline: 1.0761x; 1.0761x over previous
//
#include <hip/hip_runtime.h>
#include <stdint.h>

typedef float f32x4 __attribute__((ext_vector_type(4)));
typedef short short8 __attribute__((ext_vector_type(8)));

static __device__ __forceinline__ unsigned short f2bf(float f){
  union { float f; unsigned int u; } v; v.f = f;
  unsigned int r = v.u + 0x7fffu + ((v.u >> 16) & 1u);
  return (unsigned short)(r >> 16);
}

static __device__ __forceinline__ void async16(const unsigned short* lds, const unsigned short* g){
  __builtin_amdgcn_global_load_lds(
      (const __attribute__((address_space(1))) void*)g,
      (__attribute__((address_space(3))) void*)lds, 16, 0, 0);
}

// ---------------- f32 -> bf16 conversion ----------------
__global__ void cvt_f32_bf16(const float* __restrict__ in, unsigned short* __restrict__ out, int n4){
  int i = blockIdx.x * 256 + threadIdx.x;
  const int stride = gridDim.x * 256;
  for (; i < n4; i += stride){
    const float4 v = ((const float4*)in)[i];
    ushort4 o;
    o.x = f2bf(v.x); o.y = f2bf(v.y); o.z = f2bf(v.z); o.w = f2bf(v.w);
    ((ushort4*)out)[i] = o;
  }
}

// ---------------- mask dtype detector ----------------
__global__ void detect_mask(const unsigned int* __restrict__ mask, int* __restrict__ flag){
  __shared__ int fbyte, ff32;
  const int tid = threadIdx.x;
  if (tid == 0){ fbyte = 0; ff32 = 0; }
  __syncthreads();
  int lb = 0, lf = 0;
  for (int i = tid; i < 65536; i += 256){
    unsigned int w = mask[i];
    if (w == 0x3f800000u) lf = 1;
    else if (w > 1u) lb = 1;
  }
  if (lf) atomicOr(&ff32, 1);
  if (lb) atomicOr(&fbyte, 1);
  __syncthreads();
  if (tid == 0) *flag = ff32 ? 2 : (fbyte ? 1 : 0);
}

// ============ 256x256x64 8-wave pipelined GEMM  C = A * B^T ============
// A:[M,K] rm bf16, B:[N,K] rm bf16. M%256==0, N%256==0, K%64==0.
// LDS (dynamic 128 KiB): A[2buf][2slice][256][32] + B same. Unit = (A+B) one
// 32-col k-slice = 4 global_load_lds; prefetch distance 2 units -> vmcnt(8).
// Swizzle: chunk16 ^= (row>>1)&3 applied to global SRC (linear LDS dest) and
// to ds_read addresses.
// EPI 0: f32   1: (acc+bias[col])*scale[col]->bf16   2: acc+bias[col]->bf16   3: bf16
template<int EPI>
__global__ __launch_bounds__(512, 2) void gemm256(
    const unsigned short* __restrict__ A,
    const unsigned short* __restrict__ B,
    void* __restrict__ C,
    int K, int lda, int ldb, int ldc,
    long sA, long sB, long sC,
    const float* __restrict__ bias,
    const float* __restrict__ scale)
{
  extern __shared__ unsigned short lds[];
  unsigned short* ldsA = lds;            // [2][2][256][32] = 32768 el
  unsigned short* ldsB = lds + 32768;

  const int bz = blockIdx.z;
  A += bz * sA;
  B += bz * sB;
  const int bm = blockIdx.y, bn = blockIdx.x;
  const int tid = threadIdx.x;
  const int lane = tid & 63, wave = tid >> 6;
  const int wr = wave >> 2, wc = wave & 3;         // 2 x 4 waves
  const int lr = lane & 15, lk = lane >> 4;

  // staging: thread t -> phys (row=srow(+128j), chunk=t&3); fetch logical
  // chunk (t&3)^((t>>3)&3) so that phys holds the swizzled layout.
  const int srow = tid >> 2;
  const int schunk = (tid & 3) ^ ((tid >> 3) & 3);
  const unsigned short* Ag0 = A + (long)(bm*256 +       srow)*lda + schunk*8;
  const unsigned short* Ag1 = A + (long)(bm*256 + 128 + srow)*lda + schunk*8;
  const unsigned short* Bg0 = B + (long)(bn*256 +       srow)*ldb + schunk*8;
  const unsigned short* Bg1 = B + (long)(bn*256 + 128 + srow)*ldb + schunk*8;
  const int stDst = tid * 8;

  // fragment read offsets (elements), swizzled chunk
  const int rchunk = lk ^ ((lr >> 1) & 3);
  int aOff[8], bOff[4];
  #pragma unroll
  for (int i=0;i<8;i++) aOff[i] = (wr*128 + i*16 + lr)*32 + rchunk*8;
  #pragma unroll
  for (int j=0;j<4;j++) bOff[j] = (wc*64  + j*16 + lr)*32 + rchunk*8;

  f32x4 acc[8][4];
  #pragma unroll
  for (int i=0;i<8;i++)
    #pragma unroll
    for (int j=0;j<4;j++)
      acc[i][j] = {0.f,0.f,0.f,0.f};

  const int KT = K >> 6;

  auto STAGE = [&](int t, int s, int b){
    const int dst = b*16384 + s*8192 + stDst;
    const int koff = t*64 + s*32;
    async16(ldsA + dst,        Ag0 + koff);
    async16(ldsA + dst + 4096, Ag1 + koff);
    async16(ldsB + dst,        Bg0 + koff);
    async16(ldsB + dst + 4096, Bg1 + koff);
  };

  auto DSCOMPUTE = [&](int s, int b){
    const int base = b*16384 + s*8192;
    short8 af[8], bf[4];
    #pragma unroll
    for (int i=0;i<8;i++) af[i] = *(const short8*)(ldsA + base + aOff[i]);
    #pragma unroll
    for (int j=0;j<4;j++) bf[j] = *(const short8*)(ldsB + base + bOff[j]);
    __builtin_amdgcn_s_setprio(1);
    #pragma unroll
    for (int i=0;i<8;i++)
      #pragma unroll
      for (int j=0;j<4;j++)
        acc[i][j] = __builtin_amdgcn_mfma_f32_16x16x32_bf16(af[i], bf[j], acc[i][j], 0, 0, 0);
    __builtin_amdgcn_s_setprio(0);
  };

  // prologue: tile 0 both slices into buf 0  (8 loads in flight)
  STAGE(0, 0, 0);
  STAGE(0, 1, 0);

  for (int t = 0; t < KT; ++t){
    const int b = t & 1;
    if (t + 1 < KT){
      STAGE(t+1, 0, b^1);
      asm volatile("s_waitcnt vmcnt(8)" ::: "memory");
    } else {
      asm volatile("s_waitcnt vmcnt(4)" ::: "memory");
    }
    __builtin_amdgcn_s_barrier();
    DSCOMPUTE(0, b);

    if (t + 1 < KT){
      STAGE(t+1, 1, b^1);
      asm volatile("s_waitcnt vmcnt(8)" ::: "memory");
    } else {
      asm volatile("s_waitcnt vmcnt(0)" ::: "memory");
    }
    __builtin_amdgcn_s_barrier();
    DSCOMPUTE(1, b);
  }

  // epilogue
  const long rowb = (long)bm*256 + wr*128;
  const long colb = (long)bn*256 + wc*64;
  const int cr0 = lk*4, cc0 = lr;
  #pragma unroll
  for (int i=0;i<8;i++){
    #pragma unroll
    for (int j=0;j<4;j++){
      #pragma unroll
      for (int r=0;r<4;r++){
        const long row = rowb + i*16 + cr0 + r;
        const long col = colb + j*16 + cc0;
        const float v = acc[i][j][r];
        if (EPI == 0){
          ((float*)C)[(long)bz*sC + row*ldc + col] = v;
        } else if (EPI == 1){
          ((unsigned short*)C)[(long)bz*sC + row*ldc + col] = f2bf((v + bias[col]) * scale[col]);
        } else if (EPI == 2){
          ((unsigned short*)C)[(long)bz*sC + row*ldc + col] = f2bf(v + bias[col]);
        } else {
          ((unsigned short*)C)[(long)bz*sC + row*ldc + col] = f2bf(v);
        }
      }
    }
  }
}

// ---------------- fused mask + row softmax (in-place, writes bf16 E) ----------------
// Safe in-place: all loads complete before first __syncthreads; stores after second.
__global__ __launch_bounds__(256) void mask_softmax(
    float* __restrict__ UV, const void* __restrict__ mask, const int* __restrict__ flag)
{
  const long row = blockIdx.x;
  const float4* r4 = (const float4*)(UV + row * 3072l);
  const int mode = *flag;
  const int tid = threadIdx.x;

  float4 x[3]; uint4 mk[3];
  #pragma unroll
  for (int i=0;i<3;i++) x[i] = r4[tid + i*256];

  if (mode == 0){
    const uint4* mp = (const uint4*)((const int*)mask + row*3072l);
    #pragma unroll
    for (int i=0;i<3;i++) mk[i] = mp[tid + i*256];
  } else if (mode == 1){
    const unsigned int* mp = (const unsigned int*)((const unsigned char*)mask + row*3072l);
    #pragma unroll
    for (int i=0;i<3;i++){
      unsigned int w = mp[tid + i*256];
      mk[i].x = w & 0xffu; mk[i].y = (w>>8) & 0xffu; mk[i].z = (w>>16) & 0xffu; mk[i].w = (w>>24) & 0xffu;
    }
  } else {
    const float4* mp = (const float4*)((const float*)mask + row*3072l);
    #pragma unroll
    for (int i=0;i<3;i++){
      float4 w = mp[tid + i*256];
      mk[i].x = (w.x != 0.f); mk[i].y = (w.y != 0.f); mk[i].z = (w.z != 0.f); mk[i].w = (w.w != 0.f);
    }
  }

  float mx = -3.0e38f;
  #pragma unroll
  for (int i=0;i<3;i++){
    if (!mk[i].x) mx = fmaxf(mx, x[i].x);
    if (!mk[i].y) mx = fmaxf(mx, x[i].y);
    if (!mk[i].z) mx = fmaxf(mx, x[i].z);
    if (!mk[i].w) mx = fmaxf(mx, x[i].w);
  }
  #pragma unroll
  for (int o=1;o<64;o<<=1) mx = fmaxf(mx, __shfl_xor(mx, o, 64));
  __shared__ float sm[4];
  __shared__ float ss[4];
  if ((tid & 63) == 0) sm[tid >> 6] = mx;
  __syncthreads();
  mx = fmaxf(fmaxf(sm[0], sm[1]), fmaxf(sm[2], sm[3]));

  float4 e[3]; float s = 0.f;
  #pragma unroll
  for (int i=0;i<3;i++){
    e[i].x = mk[i].x ? 0.f : __expf(x[i].x - mx);
    e[i].y = mk[i].y ? 0.f : __expf(x[i].y - mx);
    e[i].z = mk[i].z ? 0.f : __expf(x[i].z - mx);
    e[i].w = mk[i].w ? 0.f : __expf(x[i].w - mx);
    s += e[i].x + e[i].y + e[i].z + e[i].w;
  }
  #pragma unroll
  for (int o=1;o<64;o<<=1) s += __shfl_xor(s, o, 64);
  if ((tid & 63) == 0) ss[tid >> 6] = s;
  __syncthreads();
  s = ss[0] + ss[1] + ss[2] + ss[3];
  const float inv = 1.f / s;

  ushort4* o4 = (ushort4*)(UV + row * 3072l);   // bf16 row, stride 6144 el
  #pragma unroll
  for (int i=0;i<3;i++){
    ushort4 ov;
    ov.x = f2bf(e[i].x * inv); ov.y = f2bf(e[i].y * inv);
    ov.z = f2bf(e[i].z * inv); ov.w = f2bf(e[i].w * inv);
    o4[tid + i*256] = ov;
  }
}

// ---------------- LayerNorm(M=512) + ReLU -> bf16 ----------------
__global__ __launch_bounds__(256) void ln_relu(
    const float* __restrict__ fe, unsigned short* __restrict__ out,
    const float* __restrict__ g, const float* __restrict__ b)
{
  const long row = blockIdx.x;
  const float* r = fe + row * 512l;
  const int tid = threadIdx.x;
  const float x0 = r[tid], x1 = r[tid + 256];
  float s = x0 + x1;
  float s2 = x0*x0 + x1*x1;
  #pragma unroll
  for (int o=1;o<64;o<<=1){ s += __shfl_xor(s, o, 64); s2 += __shfl_xor(s2, o, 64); }
  __shared__ float sa[4], sb[4];
  if ((tid & 63) == 0){ sa[tid>>6] = s; sb[tid>>6] = s2; }
  __syncthreads();
  s  = sa[0] + sa[1] + sa[2] + sa[3];
  s2 = sb[0] + sb[1] + sb[2] + sb[3];
  const float mean = s * (1.f/512.f);
  const float var  = s2 * (1.f/512.f) - mean*mean;
  const float rstd = rsqrtf(var + 1e-5f);
  const float y0 = (x0 - mean) * rstd * g[tid]       + b[tid];
  const float y1 = (x1 - mean) * rstd * g[tid + 256] + b[tid + 256];
  out[row*512 + tid]       = f2bf(fmaxf(y0, 0.f));
  out[row*512 + tid + 256] = f2bf(fmaxf(y1, 0.f));
}

// ---------------- host launcher ----------------
extern "C" void kernel_launch(void* const* d_in, const int* in_sizes, int n_in,
                              void* d_out, int out_size, void* d_ws, size_t ws_size,
                              hipStream_t stream)
{
  const float* feature = (const float*)d_in[0];
  const void*  mask    = d_in[1];
  const float* U_w  = (const float*)d_in[2];
  const float* U_b  = (const float*)d_in[3];
  const float* V_w  = (const float*)d_in[4];
  const float* V_b  = (const float*)d_in[5];
  const float* w_a  = (const float*)d_in[6];
  const float* W_e2 = (const float*)d_in[7];
  const float* W_e1 = (const float*)d_in[8];
  const float* ln_g = (const float*)d_in[9];
  const float* ln_b = (const float*)d_in[10];

  // B=8, TN=3072, D=1024, M=512
  char* w = (char*)d_ws;
  int*            flag = (int*)w;                                   // 256 B
  unsigned short* fbf  = (unsigned short*)(w + 256);                // 24576x1024 bf16
  unsigned short* Uwb  = fbf  + 25165824;                           // 1024x1024
  unsigned short* Vwb  = Uwb  + 1048576;
  unsigned short* We2b = Vwb  + 1048576;                            // 512x1024
  unsigned short* We1b = We2b + 524288;                             // 1024x512
  unsigned short* fUb  = We1b + 524288;                             // 24576x1024
  unsigned short* fVb  = fUb  + 25165824;
  float*          UV   = (float*)(fVb + 25165824);                  // 8x3072x3072 f32
  unsigned short* fWT  = (unsigned short*)(UV + 75497472);          // 512x24576 bf16
  float*          fe   = (float*)fUb;                               // alias (fU dead after UV)
  unsigned short* fact = fVb;                                       // alias (fV dead after UV)

  // opt in to 128 KiB dynamic LDS for all gemm256 instantiations
  {
    void (*p0)(const unsigned short*, const unsigned short*, void*, int,int,int,int, long,long,long, const float*, const float*) = gemm256<0>;
    void (*p1)(const unsigned short*, const unsigned short*, void*, int,int,int,int, long,long,long, const float*, const float*) = gemm256<1>;
    void (*p2)(const unsigned short*, const unsigned short*, void*, int,int,int,int, long,long,long, const float*, const float*) = gemm256<2>;
    void (*p3)(const unsigned short*, const unsigned short*, void*, int,int,int,int, long,long,long, const float*, const float*) = gemm256<3>;
    hipFuncSetAttribute((const void*)p0, hipFuncAttributeMaxDynamicSharedMemorySize, 131072);
    hipFuncSetAttribute((const void*)p1, hipFuncAttributeMaxDynamicSharedMemorySize, 131072);
    hipFuncSetAttribute((const void*)p2, hipFuncAttributeMaxDynamicSharedMemorySize, 131072);
    hipFuncSetAttribute((const void*)p3, hipFuncAttributeMaxDynamicSharedMemorySize, 131072);
  }

  cvt_f32_bf16<<<2048, 256, 0, stream>>>(feature, fbf, 25165824/4);
  cvt_f32_bf16<<<512,  256, 0, stream>>>(U_w,  Uwb,  1048576/4);
  cvt_f32_bf16<<<512,  256, 0, stream>>>(V_w,  Vwb,  1048576/4);
  cvt_f32_bf16<<<256,  256, 0, stream>>>(W_e2, We2b, 524288/4);
  cvt_f32_bf16<<<256,  256, 0, stream>>>(W_e1, We1b, 524288/4);
  detect_mask<<<1, 256, 0, stream>>>((const unsigned int*)mask, flag);

  // fU = (f @ U_w^T + U_b) * w_a   — flattened M=24576
  gemm256<1><<<dim3(4, 96, 1), 512, 131072, stream>>>(fbf, Uwb, fUb,
      1024, 1024, 1024, 1024, 0, 0, 0, U_b, w_a);
  // fV = f @ V_w^T + V_b
  gemm256<2><<<dim3(4, 96, 1), 512, 131072, stream>>>(fbf, Vwb, fVb,
      1024, 1024, 1024, 1024, 0, 0, 0, V_b, nullptr);
  // UV = fU @ fV^T   [3072,3072] f32 per batch
  gemm256<0><<<dim3(12, 12, 8), 512, 131072, stream>>>(fUb, fVb, UV,
      1024, 1024, 1024, 3072, 3072l*1024, 3072l*1024, 3072l*3072, nullptr, nullptr);
  // E = softmax(mask ? -inf : UV)  -> bf16 in-place (row stride 6144 el)
  mask_softmax<<<24576, 256, 0, stream>>>(UV, mask, flag);
  // fWT[k][n_glob] = W_e2 @ f^T  — M=512, N=24576
  gemm256<3><<<dim3(96, 2, 1), 512, 131072, stream>>>(We2b, fbf, fWT,
      1024, 1024, 1024, 24576, 0, 0, 0, nullptr, nullptr);
  // fe = E @ fW   [3072,512] f32 per batch   (B = fWT slice, ldb=24576, batch off 3072)
  gemm256<0><<<dim3(2, 12, 8), 512, 131072, stream>>>((const unsigned short*)UV, fWT, fe,
      3072, 6144, 24576, 512, 3072l*6144, 3072, 3072l*512, nullptr, nullptr);
  // LN + ReLU -> bf16
  ln_relu<<<24576, 256, 0, stream>>>(fe, fact, ln_g, ln_b);
  // out = fe_act @ W_e1^T  — flattened M=24576, f32 out
  gemm256<0><<<dim3(4, 96, 1), 512, 131072, stream>>>(fact, We1b, (float*)d_out,
      512, 512, 512, 1024, 0, 0, 0, nullptr, nullptr);
}